// Round 10
// baseline (271.799 us; speedup 1.0000x reference)
//
#include <hip/hip_runtime.h>
#include <math.h>

typedef __bf16 bf16x8 __attribute__((ext_vector_type(8)));
typedef _Float16 f16x8 __attribute__((ext_vector_type(8)));
typedef _Float16 f16x4 __attribute__((ext_vector_type(4)));
typedef float f32x4 __attribute__((ext_vector_type(4)));

#define LOG2E 1.44269504f
#define TWOL2E 2.88539008f

__device__ __forceinline__ unsigned short f2bf(float f) {
  unsigned int u = __builtin_bit_cast(unsigned int, f);
  u += 0x7fffu + ((u >> 16) & 1u);
  return (unsigned short)(u >> 16);
}
__device__ __forceinline__ unsigned int pack2bf(float a, float b) {
  return (unsigned int)f2bf(a) | ((unsigned int)f2bf(b) << 16);
}

// ---------- bf16 MFMA GEMM + sigmoid + avgpool2 ----------
// R26 = R25 with the pipeline ordering FIXED. R25 regression (+40us) was
// STAGE(s) before LOAD(s+1): the stage's s_waitcnt then had zero newer
// loads in flight -> raw HBM stall every stage. Correct order (T4):
//   LOAD(s+1) issue -> STAGE(s) [counted vmcnt, slab-s+1 stays in flight]
//   -> DOMFMA(s-1) -> one barrier.
// Keeps: LDS double-buffer (1 barrier/64-K stage, half of R22), R22 register
// prefetch, prep merged into gemm1's 17th x-column.
#define GK_PAD2 72
template <int WFP32, int XFP32, int DO_PREP>
__global__ __launch_bounds__(256) void gemm_mfma_sig_pool(
    const void* __restrict__ Wv, const float* __restrict__ bias,
    const void* __restrict__ Xv, void* __restrict__ Y,
    int K, int Np, int out_bf16,
    const float* __restrict__ Whh, const float* __restrict__ b3,
    _Float16* __restrict__ P) {
  if (DO_PREP && blockIdx.x == 16) {
    // prep: Whh -> fp16, hid-interleaved rows, K-stride 128, exp2-prescale.
    const int base = blockIdx.y * 256 + threadIdx.x;
    for (int idx = base; idx < 400 * 16; idx += 4096) {
      const int row = idx >> 4, ch = idx & 15;
      const int hid = row >> 2, gate = row & 3;
      const int src = gate * 100 + hid;
      const float s = (gate == 2) ? TWOL2E : LOG2E;
      f16x8 v;
#pragma unroll
      for (int j = 0; j < 8; j++) {
        const int k = ch * 8 + j;
        float f = 0.f;
        if (k < 100) f = Whh[(size_t)src * 100 + k] * s;
        v[j] = (_Float16)f;
      }
      *(f16x8*)&P[(size_t)row * 128 + ch * 8] = v;
    }
    return;
  }

  __shared__ unsigned short Wt[2][64][GK_PAD2];
  __shared__ unsigned short Xt[2][16][GK_PAD2];
  const int tid = threadIdx.x;
  const int i_base = blockIdx.x * 64;
  const int b_base = blockIdx.y * 16;
  const int srow = tid >> 2, sseg = tid & 3;   // W stage: 64 rows x 4 segs of 16
  const int xr = tid >> 4, xs = tid & 15;      // X stage: 16 rows x 16 segs of 4
  const int wv = tid >> 6, lane = tid & 63;
  const int L15 = lane & 15, q = lane >> 4;

  const float* Wf = (const float*)Wv;
  const float* Xf = (const float*)Xv;
  const unsigned short* Wh = (const unsigned short*)Wv;
  const unsigned short* Xh = (const unsigned short*)Xv;

  float4 wf[2][4];
  uint4 wh[2][2];
  float4 xf[2];
  uint2 xh2[2];

#define LOADW(S, KO)                                                          \
  do {                                                                        \
    if (WFP32) {                                                              \
      _Pragma("unroll") for (int j = 0; j < 4; j++)                           \
          wf[S][j] = *(const float4*)&Wf[(size_t)(i_base + srow) * K + (KO) + \
                                         sseg * 16 + 4 * j];                  \
    } else {                                                                  \
      _Pragma("unroll") for (int j = 0; j < 2; j++)                           \
          wh[S][j] = *(const uint4*)&Wh[(size_t)(i_base + srow) * K + (KO) +  \
                                        sseg * 16 + 8 * j];                   \
    }                                                                         \
  } while (0)

#define LOADX(S, KO)                                                          \
  do {                                                                        \
    if (XFP32) {                                                              \
      xf[S] = *(const float4*)&Xf[(size_t)(b_base + xr) * K + (KO) + xs * 4]; \
    } else {                                                                  \
      xh2[S] = *(const uint2*)&Xh[(size_t)(b_base + xr) * K + (KO) + xs * 4]; \
    }                                                                         \
  } while (0)

#define STAGEW(S, PB)                                                         \
  do {                                                                        \
    if (WFP32) {                                                              \
      uint4 p0 = {pack2bf(wf[S][0].x, wf[S][0].y),                            \
                  pack2bf(wf[S][0].z, wf[S][0].w),                            \
                  pack2bf(wf[S][1].x, wf[S][1].y),                            \
                  pack2bf(wf[S][1].z, wf[S][1].w)};                           \
      uint4 p1 = {pack2bf(wf[S][2].x, wf[S][2].y),                            \
                  pack2bf(wf[S][2].z, wf[S][2].w),                            \
                  pack2bf(wf[S][3].x, wf[S][3].y),                            \
                  pack2bf(wf[S][3].z, wf[S][3].w)};                           \
      *(uint4*)&Wt[PB][srow][sseg * 16] = p0;                                 \
      *(uint4*)&Wt[PB][srow][sseg * 16 + 8] = p1;                             \
    } else {                                                                  \
      *(uint4*)&Wt[PB][srow][sseg * 16] = wh[S][0];                           \
      *(uint4*)&Wt[PB][srow][sseg * 16 + 8] = wh[S][1];                       \
    }                                                                         \
  } while (0)

#define STAGEX(S, PB)                                                         \
  do {                                                                        \
    if (XFP32) {                                                              \
      uint2 p = {pack2bf(xf[S].x, xf[S].y), pack2bf(xf[S].z, xf[S].w)};       \
      *(uint2*)&Xt[PB][xr][xs * 4] = p;                                       \
    } else {                                                                  \
      *(uint2*)&Xt[PB][xr][xs * 4] = xh2[S];                                  \
    }                                                                         \
  } while (0)

#define DOMFMA(PB)                                                            \
  do {                                                                        \
    _Pragma("unroll") for (int kt = 0; kt < 2; kt++) {                        \
      bf16x8 a = *(const bf16x8*)&Wt[PB][wv * 16 + L15][kt * 32 + q * 8];     \
      bf16x8 b = *(const bf16x8*)&Xt[PB][L15][kt * 32 + q * 8];               \
      acc = __builtin_amdgcn_mfma_f32_16x16x32_bf16(a, b, acc, 0, 0, 0);      \
    }                                                                         \
  } while (0)

  f32x4 acc = {};
  const int S = K >> 6;  // 64-K stages (16 for K=1024, 8 for K=512)
  LOADW(0, 0);
  LOADX(0, 0);
  STAGEW(0, 0);          // waits slab0 (unavoidable initial stall)
  STAGEX(0, 0);
  LOADW(1, 64);          // slab1 in flight across the barrier
  LOADX(1, 64);
  __syncthreads();
  for (int s = 1; s < S; s++) {
    if (s + 1 < S) {     // issue slab s+1 BEFORE waiting on slab s
      LOADW((s + 1) & 1, 64 * (s + 1));
      LOADX((s + 1) & 1, 64 * (s + 1));
    }
    STAGEW(s & 1, s & 1);   // counted vmcnt: slab s+1 stays in flight
    STAGEX(s & 1, s & 1);
    DOMFMA((s - 1) & 1);
    __syncthreads();
  }
  DOMFMA((S - 1) & 1);
#undef LOADW
#undef LOADX
#undef STAGEW
#undef STAGEX
#undef DOMFMA

  // epilogue: rows i_base+16*wv+q*4 .. +3, batch col b_base+L15
  {
    const int nrow = i_base + 16 * wv + q * 4;
    const float bi0 = bias[nrow], bi1 = bias[nrow + 1];
    const float bi2 = bias[nrow + 2], bi3 = bias[nrow + 3];
    const int b = b_base + L15;
    const float a0 = __builtin_amdgcn_rcpf(1.f + __expf(-(acc[0] + bi0)));
    const float a1 = __builtin_amdgcn_rcpf(1.f + __expf(-(acc[1] + bi1)));
    const float a2 = __builtin_amdgcn_rcpf(1.f + __expf(-(acc[2] + bi2)));
    const float a3 = __builtin_amdgcn_rcpf(1.f + __expf(-(acc[3] + bi3)));
    const float p0 = 0.5f * (a0 + a1), p1 = 0.5f * (a2 + a3);
    const int pidx = nrow >> 1;  // even
    if (out_bf16) {
      *(unsigned int*)&((unsigned short*)Y)[(size_t)b * Np + pidx] = pack2bf(p0, p1);
    } else {
      *(float2*)&((float*)Y)[(size_t)b * Np + pidx] = make_float2(p0, p1);
    }
  }
}

// ---------- MFMA LSTM (byte-identical to R22's measured 133.5us) ----------
// Frozen: R17 dense (205), R18 16-wave (200), R20 tail-fold (145), R24
// dual-batch (206) all regressed vs this structure. Step is barrier+LDS
// roundtrip latency-pinned; barrier cost scales with wave count.
#define TSTEPS 256

__device__ __forceinline__ float qb0(float x) {
  return __builtin_bit_cast(float, __builtin_amdgcn_mov_dpp(__builtin_bit_cast(int, x), 0x00, 0xf, 0xf, true));
}
__device__ __forceinline__ float qb1(float x) {
  return __builtin_bit_cast(float, __builtin_amdgcn_mov_dpp(__builtin_bit_cast(int, x), 0x55, 0xf, 0xf, true));
}
__device__ __forceinline__ float qb2(float x) {
  return __builtin_bit_cast(float, __builtin_amdgcn_mov_dpp(__builtin_bit_cast(int, x), 0xAA, 0xf, 0xf, true));
}
__device__ __forceinline__ float qb3(float x) {
  return __builtin_bit_cast(float, __builtin_amdgcn_mov_dpp(__builtin_bit_cast(int, x), 0xFF, 0xf, 0xf, true));
}

__global__ __launch_bounds__(512, 2) void lstm_mfma(
    const float* __restrict__ X, const _Float16* __restrict__ P,
    const float* __restrict__ Whh, const float* __restrict__ Wih,
    const float* __restrict__ b3, const float* __restrict__ Wout,
    const float* __restrict__ bout, float* __restrict__ out) {
  const int bat = blockIdx.x;
  const int t = threadIdx.x;
  const int w = t >> 6, lane = t & 63;
  const int quad = lane >> 4, c = lane & 15;
  const int TB = (w == 7) ? 21 : w * 3;   // tile base
  const int NT = (w == 7) ? 4 : 3;        // tiles this wave activates

  __shared__ __align__(16) _Float16 hbuf[2][128];
  __shared__ float xrow[TSTEPS];
  __shared__ float red[128];

  for (int i = t; i < TSTEPS; i += 512) xrow[i] = X[(size_t)bat * TSTEPS + i];
  if (t < 128) { hbuf[0][t] = (_Float16)0.f; hbuf[1][t] = (_Float16)0.f; }

#define LDA(J, KT) const f16x8 A##J##KT = \
    *(const f16x8*)&P[(size_t)((TB + J) * 16 + c) * 128 + (KT) * 32 + quad * 8];
  LDA(0,0) LDA(0,1) LDA(0,2)
  LDA(1,0) LDA(1,1) LDA(1,2)
  LDA(2,0) LDA(2,1) LDA(2,2)
  LDA(3,0) LDA(3,1) LDA(3,2)
#undef LDA

  // activation role: lane handles gate g of hid 4*(TB+J)+quad
  const bool act = (c < 4 * NT);
  const int J = c >> 2, g = c & 3;
  const int myhid = 4 * (TB + (act ? J : 0)) + quad;  // < 100
  const int grow = g * 100 + myhid;                   // gate-major row
  const float sc = (g == 2) ? TWOL2E : LOG2E;         // exp2 prescale
  const float u_ = Wih[grow] * sc;
  const float bz = b3[grow] * sc;
  const float4 wt0 = *(const float4*)&Whh[(size_t)grow * 100 + 96];  // k 96..99
  const float4 wt = make_float4(wt0.x * sc, wt0.y * sc, wt0.z * sc, wt0.w * sc);
  const float mm = (g == 2) ? 2.f : 1.f;   // g-gate is tanh = 2*sig(2z)-1
  const float dd = (g == 2) ? -1.f : 0.f;
  float cst = 0.f;
  __syncthreads();

#define SIG2(zz) __builtin_amdgcn_rcpf(1.f + __builtin_amdgcn_exp2f(-(zz)))
#define STEPB(HC, HN, XT)                                                      \
  {                                                                            \
    const _Float16* hc = (HC);                                                 \
    const f16x8 B0 = *(const f16x8*)&hc[0 * 32 + quad * 8];                    \
    const f16x8 B1 = *(const f16x8*)&hc[1 * 32 + quad * 8];                    \
    const f16x8 B2 = *(const f16x8*)&hc[2 * 32 + quad * 8];                    \
    f32x4 z0 = {0.f,0.f,0.f,0.f}, z1 = z0, z2 = z0, z3 = z0;                   \
    { f32x4 za = z0, zb = z0;                                                  \
      za = __builtin_amdgcn_mfma_f32_16x16x32_f16(A00, B0, za, 0, 0, 0);       \
      zb = __builtin_amdgcn_mfma_f32_16x16x32_f16(A01, B1, zb, 0, 0, 0);       \
      za = __builtin_amdgcn_mfma_f32_16x16x32_f16(A02, B2, za, 0, 0, 0);       \
      z0 = za + zb; }                                                          \
    { f32x4 za = {0.f,0.f,0.f,0.f}, zb = za;                                   \
      za = __builtin_amdgcn_mfma_f32_16x16x32_f16(A10, B0, za, 0, 0, 0);       \
      zb = __builtin_amdgcn_mfma_f32_16x16x32_f16(A11, B1, zb, 0, 0, 0);       \
      za = __builtin_amdgcn_mfma_f32_16x16x32_f16(A12, B2, za, 0, 0, 0);       \
      z1 = za + zb; }                                                          \
    { f32x4 za = {0.f,0.f,0.f,0.f}, zb = za;                                   \
      za = __builtin_amdgcn_mfma_f32_16x16x32_f16(A20, B0, za, 0, 0, 0);       \
      zb = __builtin_amdgcn_mfma_f32_16x16x32_f16(A21, B1, zb, 0, 0, 0);       \
      za = __builtin_amdgcn_mfma_f32_16x16x32_f16(A22, B2, za, 0, 0, 0);       \
      z2 = za + zb; }                                                          \
    if (w == 7) {                                                              \
      f32x4 za = {0.f,0.f,0.f,0.f}, zb = za;                                   \
      za = __builtin_amdgcn_mfma_f32_16x16x32_f16(A30, B0, za, 0, 0, 0);       \
      zb = __builtin_amdgcn_mfma_f32_16x16x32_f16(A31, B1, zb, 0, 0, 0);       \
      za = __builtin_amdgcn_mfma_f32_16x16x32_f16(A32, B2, za, 0, 0, 0);       \
      z3 = za + zb; }                                                          \
    if (act) {                                                                 \
      const f32x4 zt = (J == 0) ? z0 : (J == 1) ? z1 : (J == 2) ? z2 : z3;     \
      float zs = (g == 0) ? zt[0] : (g == 1) ? zt[1] : (g == 2) ? zt[2] : zt[3];\
      const f16x4 ht = *(const f16x4*)&hc[96];                                 \
      zs = fmaf(wt.x, (float)ht[0], zs);                                       \
      zs = fmaf(wt.y, (float)ht[1], zs);                                       \
      zs = fmaf(wt.z, (float)ht[2], zs);                                       \
      zs = fmaf(wt.w, (float)ht[3], zs);                                       \
      zs = fmaf(u_, (XT), zs + bz);                                            \
      const float a = mm * SIG2(zs) + dd;                                      \
      const float ai = qb0(a), af = qb1(a), ag = qb2(a), ao = qb3(a);          \
      cst = fmaf(af, cst, ai * ag);                                            \
      const float th = 2.f * SIG2(TWOL2E * cst) - 1.f;                         \
      if (g == 0) (HN)[myhid] = (_Float16)(ao * th);                           \
    }                                                                          \
    __syncthreads();                                                           \
  }

  for (int step = 0; step < TSTEPS; step += 2) {
    STEPB(hbuf[0], hbuf[1], xrow[step]);
    STEPB(hbuf[1], hbuf[0], xrow[step + 1]);
  }
#undef STEPB
#undef SIG2

  // out[bat] = dot(h_final, Wout) + bout; final h in hbuf[0]
  if (t < 128) {
    float a = 0.f;
    if (t < 100) a = (float)hbuf[0][t] * Wout[t];
    red[t] = a;
  }
  __syncthreads();
  if (t == 0) {
    float s = 0.f;
#pragma unroll
    for (int k = 0; k < 128; k++) s += red[k];
    out[bat] = s + bout[0];
  }
}

// ---------- launch ----------
extern "C" void kernel_launch(void* const* d_in, const int* in_sizes, int n_in,
                              void* d_out, int out_size, void* d_ws, size_t ws_size,
                              hipStream_t stream) {
  const float* x    = (const float*)d_in[0];   // (256,1024)
  const float* W1L  = (const float*)d_in[3];   // (1024,1024)
  const float* b1L  = (const float*)d_in[4];
  const float* W2L  = (const float*)d_in[7];   // (512,512)
  const float* b2L  = (const float*)d_in[8];
  const float* Wih3 = (const float*)d_in[15];  // (400,1)
  const float* Whh3 = (const float*)d_in[16];  // (400,100)
  const float* b3   = (const float*)d_in[17];  // (400,)
  const float* Wout = (const float*)d_in[18];  // (1,100)
  const float* bout = (const float*)d_in[19];  // (1,)
  float* out = (float*)d_out;                  // (256,)

  unsigned short* xl1b = (unsigned short*)d_ws;        // 256x512 bf16
  float* xl2 = (float*)(xl1b + (size_t)256 * 512);     // 256x256 f32
  _Float16* P = (_Float16*)(xl2 + (size_t)256 * 256);  // 400x128 fp16

  // gemm1 carries prep in its 17th x-block-column
  gemm_mfma_sig_pool<1, 1, 1><<<dim3(17, 16), 256, 0, stream>>>(
      W1L, b1L, x, xl1b, 1024, 512, 1, Whh3, b3, P);
  gemm_mfma_sig_pool<1, 0, 0><<<dim3(8, 16), 256, 0, stream>>>(
      W2L, b2L, xl1b, xl2, 512, 256, 0, nullptr, nullptr, nullptr);
  lstm_mfma<<<256, 512, 0, stream>>>(xl2, P, Whh3, Wih3, b3, Wout, bout, out);
}

// Round 11
// 233.109 us; speedup vs baseline: 1.1660x; 1.1660x over previous
//
#include <hip/hip_runtime.h>
#include <math.h>

typedef __bf16 bf16x8 __attribute__((ext_vector_type(8)));
typedef _Float16 f16x8 __attribute__((ext_vector_type(8)));
typedef _Float16 f16x4 __attribute__((ext_vector_type(4)));
typedef float f32x4 __attribute__((ext_vector_type(4)));

__device__ __forceinline__ unsigned short f2bf(float f) {
  unsigned int u = __builtin_bit_cast(unsigned int, f);
  u += 0x7fffu + ((u >> 16) & 1u);
  return (unsigned short)(u >> 16);
}
__device__ __forceinline__ unsigned int pack2bf(float a, float b) {
  return (unsigned int)f2bf(a) | ((unsigned int)f2bf(b) << 16);
}

// ---------- bf16 MFMA GEMM + sigmoid + avgpool2 (EXACT R22, measured 231.1) --
// R25/R26 post-mortem: the single-barrier LDS-double-buffer variant is +40us
// vs this and the mechanism is not understood (reorder fix changed nothing).
// Unexplained regressions get reverted, not re-patched. This is the proven
// R22 code: 64x16 tile, BK=64, register double-buffer prefetch, 2 barriers
// per 64-K slab, grid (16,16)/(8,16) = full chip.
#define GK_PAD2 72
template <int WFP32, int XFP32>
__global__ __launch_bounds__(256) void gemm_mfma_sig_pool(
    const void* __restrict__ Wv, const float* __restrict__ bias,
    const void* __restrict__ Xv, void* __restrict__ Y,
    int K, int Np, int out_bf16) {
  __shared__ unsigned short Wt[64][GK_PAD2];
  __shared__ unsigned short Xt[16][GK_PAD2];
  const int tid = threadIdx.x;
  const int i_base = blockIdx.x * 64;
  const int b_base = blockIdx.y * 16;
  const int srow = tid >> 2, sseg = tid & 3;   // W stage: 64 rows x 4 segs of 16
  const int xr = tid >> 4, xs = tid & 15;      // X stage: 16 rows x 16 segs of 4
  const int wv = tid >> 6, lane = tid & 63;
  const int L15 = lane & 15, q = lane >> 4;

  const float* Wf = (const float*)Wv;
  const float* Xf = (const float*)Xv;
  const unsigned short* Wh = (const unsigned short*)Wv;
  const unsigned short* Xh = (const unsigned short*)Xv;

  float4 wf[2][4];
  uint4 wh[2][2];
  float4 xf[2];
  uint2 xh2[2];

#define LOADW(S, KO)                                                          \
  do {                                                                        \
    if (WFP32) {                                                              \
      _Pragma("unroll") for (int j = 0; j < 4; j++)                           \
          wf[S][j] = *(const float4*)&Wf[(size_t)(i_base + srow) * K + (KO) + \
                                         sseg * 16 + 4 * j];                  \
    } else {                                                                  \
      _Pragma("unroll") for (int j = 0; j < 2; j++)                           \
          wh[S][j] = *(const uint4*)&Wh[(size_t)(i_base + srow) * K + (KO) +  \
                                        sseg * 16 + 8 * j];                   \
    }                                                                         \
  } while (0)

#define LOADX(S, KO)                                                          \
  do {                                                                        \
    if (XFP32) {                                                              \
      xf[S] = *(const float4*)&Xf[(size_t)(b_base + xr) * K + (KO) + xs * 4]; \
    } else {                                                                  \
      xh2[S] = *(const uint2*)&Xh[(size_t)(b_base + xr) * K + (KO) + xs * 4]; \
    }                                                                         \
  } while (0)

#define STAGEW(S)                                                             \
  do {                                                                        \
    if (WFP32) {                                                              \
      uint4 p0 = {pack2bf(wf[S][0].x, wf[S][0].y),                            \
                  pack2bf(wf[S][0].z, wf[S][0].w),                            \
                  pack2bf(wf[S][1].x, wf[S][1].y),                            \
                  pack2bf(wf[S][1].z, wf[S][1].w)};                           \
      uint4 p1 = {pack2bf(wf[S][2].x, wf[S][2].y),                            \
                  pack2bf(wf[S][2].z, wf[S][2].w),                            \
                  pack2bf(wf[S][3].x, wf[S][3].y),                            \
                  pack2bf(wf[S][3].z, wf[S][3].w)};                           \
      *(uint4*)&Wt[srow][sseg * 16] = p0;                                     \
      *(uint4*)&Wt[srow][sseg * 16 + 8] = p1;                                 \
    } else {                                                                  \
      *(uint4*)&Wt[srow][sseg * 16] = wh[S][0];                               \
      *(uint4*)&Wt[srow][sseg * 16 + 8] = wh[S][1];                           \
    }                                                                         \
  } while (0)

#define STAGEX(S)                                                             \
  do {                                                                        \
    if (XFP32) {                                                              \
      uint2 p = {pack2bf(xf[S].x, xf[S].y), pack2bf(xf[S].z, xf[S].w)};       \
      *(uint2*)&Xt[xr][xs * 4] = p;                                           \
    } else {                                                                  \
      *(uint2*)&Xt[xr][xs * 4] = xh2[S];                                      \
    }                                                                         \
  } while (0)

#define DOMFMA                                                                \
  do {                                                                        \
    _Pragma("unroll") for (int kt = 0; kt < 2; kt++) {                        \
      bf16x8 a = *(const bf16x8*)&Wt[wv * 16 + L15][kt * 32 + q * 8];         \
      bf16x8 b = *(const bf16x8*)&Xt[L15][kt * 32 + q * 8];                   \
      acc = __builtin_amdgcn_mfma_f32_16x16x32_bf16(a, b, acc, 0, 0, 0);      \
    }                                                                         \
  } while (0)

  f32x4 acc = {};
  LOADW(0, 0);
  LOADX(0, 0);
  for (int k0 = 0; k0 < K; k0 += 128) {
    LOADW(1, k0 + 64);  // k0+64 < K always (K multiple of 128)
    LOADX(1, k0 + 64);
    STAGEW(0);
    STAGEX(0);
    __syncthreads();
    DOMFMA;
    __syncthreads();
    if (k0 + 128 < K) {
      LOADW(0, k0 + 128);
      LOADX(0, k0 + 128);
    }
    STAGEW(1);
    STAGEX(1);
    __syncthreads();
    DOMFMA;
    __syncthreads();
  }
#undef LOADW
#undef LOADX
#undef STAGEW
#undef STAGEX
#undef DOMFMA

  // epilogue: rows i_base+16*wv+q*4 .. +3, batch col b_base+L15
  {
    const int nrow = i_base + 16 * wv + q * 4;
    const float bi0 = bias[nrow], bi1 = bias[nrow + 1];
    const float bi2 = bias[nrow + 2], bi3 = bias[nrow + 3];
    const int b = b_base + L15;
    const float a0 = __builtin_amdgcn_rcpf(1.f + __expf(-(acc[0] + bi0)));
    const float a1 = __builtin_amdgcn_rcpf(1.f + __expf(-(acc[1] + bi1)));
    const float a2 = __builtin_amdgcn_rcpf(1.f + __expf(-(acc[2] + bi2)));
    const float a3 = __builtin_amdgcn_rcpf(1.f + __expf(-(acc[3] + bi3)));
    const float p0 = 0.5f * (a0 + a1), p1 = 0.5f * (a2 + a3);
    const int pidx = nrow >> 1;  // even
    if (out_bf16) {
      *(unsigned int*)&((unsigned short*)Y)[(size_t)b * Np + pidx] = pack2bf(p0, p1);
    } else {
      *(float2*)&((float*)Y)[(size_t)b * Np + pidx] = make_float2(p0, p1);
    }
  }
}

// ---------- prep: Whh -> fp16, hid-interleaved rows, K-stride 128 ----------
// (EXACT R22: separate dispatch; the merged-into-gemm1 variant is confounded
// with the R25 regression and reverted with it.)
#define LOG2E 1.44269504f
#define TWOL2E 2.88539008f
__global__ __launch_bounds__(256) void prep_whh(
    const float* __restrict__ Whh, const float* __restrict__ b3,
    _Float16* __restrict__ P) {
  const int idx = blockIdx.x * 256 + threadIdx.x;  // (row, chunk-of-8)
  if (idx >= 400 * 16) return;
  const int row = idx >> 4, ch = idx & 15;
  const int hid = row >> 2, gate = row & 3;
  const int src = gate * 100 + hid;
  const float s = (gate == 2) ? TWOL2E : LOG2E;
  f16x8 v;
#pragma unroll
  for (int j = 0; j < 8; j++) {
    const int k = ch * 8 + j;
    float f = 0.f;
    if (k < 100) f = Whh[(size_t)src * 100 + k] * s;
    v[j] = (_Float16)f;
  }
  *(f16x8*)&P[(size_t)row * 128 + ch * 8] = v;
}

// ---------- MFMA LSTM (R27 = R22 + two chain-only micro-cuts) ----------
// Structure FROZEN (R17/R18/R20/R24 all regressed). Changes vs the measured
// 133.5us body, both intra-step, no sync/layout change:
//  (1) ht (hc[96..99], ds_read_b64) hoisted OUT of the divergent if(act)
//      branch to the step top: issues with B0-B2, latency hides under the
//      MFMAs instead of sitting exposed on the act chain.
//  (2) fp32 tail as two balanced z-independent trees t0/t1; chain after the
//      MFMA result shrinks from 5 serial FMAs to 2 adds.
#define TSTEPS 256

__device__ __forceinline__ float qb0(float x) {
  return __builtin_bit_cast(float, __builtin_amdgcn_mov_dpp(__builtin_bit_cast(int, x), 0x00, 0xf, 0xf, true));
}
__device__ __forceinline__ float qb1(float x) {
  return __builtin_bit_cast(float, __builtin_amdgcn_mov_dpp(__builtin_bit_cast(int, x), 0x55, 0xf, 0xf, true));
}
__device__ __forceinline__ float qb2(float x) {
  return __builtin_bit_cast(float, __builtin_amdgcn_mov_dpp(__builtin_bit_cast(int, x), 0xAA, 0xf, 0xf, true));
}
__device__ __forceinline__ float qb3(float x) {
  return __builtin_bit_cast(float, __builtin_amdgcn_mov_dpp(__builtin_bit_cast(int, x), 0xFF, 0xf, 0xf, true));
}

__global__ __launch_bounds__(512, 2) void lstm_mfma(
    const float* __restrict__ X, const _Float16* __restrict__ P,
    const float* __restrict__ Whh, const float* __restrict__ Wih,
    const float* __restrict__ b3, const float* __restrict__ Wout,
    const float* __restrict__ bout, float* __restrict__ out) {
  const int bat = blockIdx.x;
  const int t = threadIdx.x;
  const int w = t >> 6, lane = t & 63;
  const int quad = lane >> 4, c = lane & 15;
  const int TB = (w == 7) ? 21 : w * 3;   // tile base
  const int NT = (w == 7) ? 4 : 3;        // tiles this wave activates

  __shared__ __align__(16) _Float16 hbuf[2][128];
  __shared__ float xrow[TSTEPS];
  __shared__ float red[128];

  for (int i = t; i < TSTEPS; i += 512) xrow[i] = X[(size_t)bat * TSTEPS + i];
  if (t < 128) { hbuf[0][t] = (_Float16)0.f; hbuf[1][t] = (_Float16)0.f; }

#define LDA(J, KT) const f16x8 A##J##KT = \
    *(const f16x8*)&P[(size_t)((TB + J) * 16 + c) * 128 + (KT) * 32 + quad * 8];
  LDA(0,0) LDA(0,1) LDA(0,2)
  LDA(1,0) LDA(1,1) LDA(1,2)
  LDA(2,0) LDA(2,1) LDA(2,2)
  LDA(3,0) LDA(3,1) LDA(3,2)
#undef LDA

  // activation role: lane handles gate g of hid 4*(TB+J)+quad
  const bool act = (c < 4 * NT);
  const int J = c >> 2, g = c & 3;
  const int myhid = 4 * (TB + (act ? J : 0)) + quad;  // < 100
  const int grow = g * 100 + myhid;                   // gate-major row
  const float sc = (g == 2) ? TWOL2E : LOG2E;         // exp2 prescale
  const float u_ = Wih[grow] * sc;
  const float bz = b3[grow] * sc;
  const float4 wt0 = *(const float4*)&Whh[(size_t)grow * 100 + 96];  // k 96..99
  const float4 wt = make_float4(wt0.x * sc, wt0.y * sc, wt0.z * sc, wt0.w * sc);
  const float mm = (g == 2) ? 2.f : 1.f;   // g-gate is tanh = 2*sig(2z)-1
  const float dd = (g == 2) ? -1.f : 0.f;
  float cst = 0.f;
  __syncthreads();

#define SIG2(zz) __builtin_amdgcn_rcpf(1.f + __builtin_amdgcn_exp2f(-(zz)))
#define STEPB(HC, HN, XT)                                                      \
  {                                                                            \
    const _Float16* hc = (HC);                                                 \
    const f16x8 B0 = *(const f16x8*)&hc[0 * 32 + quad * 8];                    \
    const f16x8 B1 = *(const f16x8*)&hc[1 * 32 + quad * 8];                    \
    const f16x8 B2 = *(const f16x8*)&hc[2 * 32 + quad * 8];                    \
    const f16x4 ht = *(const f16x4*)&hc[96]; /* hoisted: hides under MFMAs */  \
    f32x4 z0 = {0.f,0.f,0.f,0.f}, z1 = z0, z2 = z0, z3 = z0;                   \
    { f32x4 za = z0, zb = z0;                                                  \
      za = __builtin_amdgcn_mfma_f32_16x16x32_f16(A00, B0, za, 0, 0, 0);       \
      zb = __builtin_amdgcn_mfma_f32_16x16x32_f16(A01, B1, zb, 0, 0, 0);       \
      za = __builtin_amdgcn_mfma_f32_16x16x32_f16(A02, B2, za, 0, 0, 0);       \
      z0 = za + zb; }                                                          \
    { f32x4 za = {0.f,0.f,0.f,0.f}, zb = za;                                   \
      za = __builtin_amdgcn_mfma_f32_16x16x32_f16(A10, B0, za, 0, 0, 0);       \
      zb = __builtin_amdgcn_mfma_f32_16x16x32_f16(A11, B1, zb, 0, 0, 0);       \
      za = __builtin_amdgcn_mfma_f32_16x16x32_f16(A12, B2, za, 0, 0, 0);       \
      z1 = za + zb; }                                                          \
    { f32x4 za = {0.f,0.f,0.f,0.f}, zb = za;                                   \
      za = __builtin_amdgcn_mfma_f32_16x16x32_f16(A20, B0, za, 0, 0, 0);       \
      zb = __builtin_amdgcn_mfma_f32_16x16x32_f16(A21, B1, zb, 0, 0, 0);       \
      za = __builtin_amdgcn_mfma_f32_16x16x32_f16(A22, B2, za, 0, 0, 0);       \
      z2 = za + zb; }                                                          \
    if (w == 7) {                                                              \
      f32x4 za = {0.f,0.f,0.f,0.f}, zb = za;                                   \
      za = __builtin_amdgcn_mfma_f32_16x16x32_f16(A30, B0, za, 0, 0, 0);       \
      zb = __builtin_amdgcn_mfma_f32_16x16x32_f16(A31, B1, zb, 0, 0, 0);       \
      za = __builtin_amdgcn_mfma_f32_16x16x32_f16(A32, B2, za, 0, 0, 0);       \
      z3 = za + zb; }                                                          \
    if (act) {                                                                 \
      const f32x4 zt = (J == 0) ? z0 : (J == 1) ? z1 : (J == 2) ? z2 : z3;     \
      const float zsel = (g == 0) ? zt[0] : (g == 1) ? zt[1]                   \
                       : (g == 2) ? zt[2] : zt[3];                             \
      /* z-independent balanced tail: schedules before/during the select */    \
      const float t0 = fmaf(wt.x, (float)ht[0], fmaf(wt.y, (float)ht[1], bz)); \
      const float t1 = fmaf(wt.z, (float)ht[2],                                \
                            fmaf(wt.w, (float)ht[3], u_ * (XT)));              \
      const float zs = (zsel + t0) + t1;                                       \
      const float a = mm * SIG2(zs) + dd;                                      \
      const float ai = qb0(a), af = qb1(a), ag = qb2(a), ao = qb3(a);          \
      cst = fmaf(af, cst, ai * ag);                                            \
      const float th = 2.f * SIG2(TWOL2E * cst) - 1.f;                         \
      if (g == 0) (HN)[myhid] = (_Float16)(ao * th);                           \
    }                                                                          \
    __syncthreads();                                                           \
  }

  for (int step = 0; step < TSTEPS; step += 2) {
    STEPB(hbuf[0], hbuf[1], xrow[step]);
    STEPB(hbuf[1], hbuf[0], xrow[step + 1]);
  }
#undef STEPB
#undef SIG2

  // out[bat] = dot(h_final, Wout) + bout; final h in hbuf[0]
  if (t < 128) {
    float a = 0.f;
    if (t < 100) a = (float)hbuf[0][t] * Wout[t];
    red[t] = a;
  }
  __syncthreads();
  if (t == 0) {
    float s = 0.f;
#pragma unroll
    for (int k = 0; k < 128; k++) s += red[k];
    out[bat] = s + bout[0];
  }
}

// ---------- launch (EXACT R22 dispatch sequence) ----------
extern "C" void kernel_launch(void* const* d_in, const int* in_sizes, int n_in,
                              void* d_out, int out_size, void* d_ws, size_t ws_size,
                              hipStream_t stream) {
  const float* x    = (const float*)d_in[0];   // (256,1024)
  const float* W1L  = (const float*)d_in[3];   // (1024,1024)
  const float* b1L  = (const float*)d_in[4];
  const float* W2L  = (const float*)d_in[7];   // (512,512)
  const float* b2L  = (const float*)d_in[8];
  const float* Wih3 = (const float*)d_in[15];  // (400,1)
  const float* Whh3 = (const float*)d_in[16];  // (400,100)
  const float* b3   = (const float*)d_in[17];  // (400,)
  const float* Wout = (const float*)d_in[18];  // (1,100)
  const float* bout = (const float*)d_in[19];  // (1,)
  float* out = (float*)d_out;                  // (256,)

  unsigned short* xl1b = (unsigned short*)d_ws;        // 256x512 bf16
  float* xl2 = (float*)(xl1b + (size_t)256 * 512);     // 256x256 f32
  _Float16* P = (_Float16*)(xl2 + (size_t)256 * 256);  // 400x128 fp16

  prep_whh<<<25, 256, 0, stream>>>(Whh3, b3, P);
  gemm_mfma_sig_pool<1, 1><<<dim3(16, 16), 256, 0, stream>>>(W1L, b1L, x, xl1b, 1024, 512, 1);
  gemm_mfma_sig_pool<1, 0><<<dim3(8, 16), 256, 0, stream>>>(W2L, b2L, xl1b, xl2, 512, 256, 0);
  lstm_mfma<<<256, 512, 0, stream>>>(xl2, P, Whh3, Wih3, b3, Wout, bout, out);
}

// Round 12
// 229.955 us; speedup vs baseline: 1.1820x; 1.0137x over previous
//
#include <hip/hip_runtime.h>
#include <math.h>

typedef __bf16 bf16x8 __attribute__((ext_vector_type(8)));
typedef _Float16 f16x8 __attribute__((ext_vector_type(8)));
typedef _Float16 f16x4 __attribute__((ext_vector_type(4)));
typedef float f32x4 __attribute__((ext_vector_type(4)));

#define LOG2E 1.44269504f
#define TWOL2E 2.88539008f

__device__ __forceinline__ unsigned short f2bf(float f) {
  unsigned int u = __builtin_bit_cast(unsigned int, f);
  u += 0x7fffu + ((u >> 16) & 1u);
  return (unsigned short)(u >> 16);
}
__device__ __forceinline__ unsigned int pack2bf(float a, float b) {
  return (unsigned int)f2bf(a) | ((unsigned int)f2bf(b) << 16);
}

// ---------- bf16 MFMA GEMM + sigmoid + avgpool2 (EXACT R22 pipeline) ----------
// R25/R26 post-mortem: single-barrier LDS-dbuf variant is +40us vs this and
// the mechanism is not understood -> reverted, not re-patched. This is the
// proven R22 code: 64x16 tile, BK=64, register double-buffer prefetch, 2
// barriers per 64-K slab, full-chip grids.
// R28: DO_PREP attaches the Whh->P prep as extra x==NXB blocks on gemm2's
// grid (gemm2 uses only 128 CUs; prep rides the idle 128). Zero changes to
// the GEMM path itself.
#define GK_PAD2 72
template <int WFP32, int XFP32, int DO_PREP, int NXB>
__global__ __launch_bounds__(256) void gemm_mfma_sig_pool(
    const void* __restrict__ Wv, const float* __restrict__ bias,
    const void* __restrict__ Xv, void* __restrict__ Y,
    int K, int Np, int out_bf16,
    const float* __restrict__ Whh, const float* __restrict__ b3,
    _Float16* __restrict__ P) {
  if (DO_PREP && blockIdx.x == NXB) {
    // prep: Whh -> fp16, hid-interleaved rows, K-stride 128, exp2-prescale.
    // 16 y-blocks x 256 threads x 2 items cover 400*16 = 6400 chunks.
    const int base = blockIdx.y * 256 + threadIdx.x;
    for (int idx = base; idx < 400 * 16; idx += 4096) {
      const int row = idx >> 4, ch = idx & 15;
      const int hid = row >> 2, gate = row & 3;
      const int src = gate * 100 + hid;
      const float s = (gate == 2) ? TWOL2E : LOG2E;
      f16x8 v;
#pragma unroll
      for (int j = 0; j < 8; j++) {
        const int k = ch * 8 + j;
        float f = 0.f;
        if (k < 100) f = Whh[(size_t)src * 100 + k] * s;
        v[j] = (_Float16)f;
      }
      *(f16x8*)&P[(size_t)row * 128 + ch * 8] = v;
    }
    return;
  }

  __shared__ unsigned short Wt[64][GK_PAD2];
  __shared__ unsigned short Xt[16][GK_PAD2];
  const int tid = threadIdx.x;
  const int i_base = blockIdx.x * 64;
  const int b_base = blockIdx.y * 16;
  const int srow = tid >> 2, sseg = tid & 3;   // W stage: 64 rows x 4 segs of 16
  const int xr = tid >> 4, xs = tid & 15;      // X stage: 16 rows x 16 segs of 4
  const int wv = tid >> 6, lane = tid & 63;
  const int L15 = lane & 15, q = lane >> 4;

  const float* Wf = (const float*)Wv;
  const float* Xf = (const float*)Xv;
  const unsigned short* Wh = (const unsigned short*)Wv;
  const unsigned short* Xh = (const unsigned short*)Xv;

  float4 wf[2][4];
  uint4 wh[2][2];
  float4 xf[2];
  uint2 xh2[2];

#define LOADW(S, KO)                                                          \
  do {                                                                        \
    if (WFP32) {                                                              \
      _Pragma("unroll") for (int j = 0; j < 4; j++)                           \
          wf[S][j] = *(const float4*)&Wf[(size_t)(i_base + srow) * K + (KO) + \
                                         sseg * 16 + 4 * j];                  \
    } else {                                                                  \
      _Pragma("unroll") for (int j = 0; j < 2; j++)                           \
          wh[S][j] = *(const uint4*)&Wh[(size_t)(i_base + srow) * K + (KO) +  \
                                        sseg * 16 + 8 * j];                   \
    }                                                                         \
  } while (0)

#define LOADX(S, KO)                                                          \
  do {                                                                        \
    if (XFP32) {                                                              \
      xf[S] = *(const float4*)&Xf[(size_t)(b_base + xr) * K + (KO) + xs * 4]; \
    } else {                                                                  \
      xh2[S] = *(const uint2*)&Xh[(size_t)(b_base + xr) * K + (KO) + xs * 4]; \
    }                                                                         \
  } while (0)

#define STAGEW(S)                                                             \
  do {                                                                        \
    if (WFP32) {                                                              \
      uint4 p0 = {pack2bf(wf[S][0].x, wf[S][0].y),                            \
                  pack2bf(wf[S][0].z, wf[S][0].w),                            \
                  pack2bf(wf[S][1].x, wf[S][1].y),                            \
                  pack2bf(wf[S][1].z, wf[S][1].w)};                           \
      uint4 p1 = {pack2bf(wf[S][2].x, wf[S][2].y),                            \
                  pack2bf(wf[S][2].z, wf[S][2].w),                            \
                  pack2bf(wf[S][3].x, wf[S][3].y),                            \
                  pack2bf(wf[S][3].z, wf[S][3].w)};                           \
      *(uint4*)&Wt[srow][sseg * 16] = p0;                                     \
      *(uint4*)&Wt[srow][sseg * 16 + 8] = p1;                                 \
    } else {                                                                  \
      *(uint4*)&Wt[srow][sseg * 16] = wh[S][0];                               \
      *(uint4*)&Wt[srow][sseg * 16 + 8] = wh[S][1];                           \
    }                                                                         \
  } while (0)

#define STAGEX(S)                                                             \
  do {                                                                        \
    if (XFP32) {                                                              \
      uint2 p = {pack2bf(xf[S].x, xf[S].y), pack2bf(xf[S].z, xf[S].w)};       \
      *(uint2*)&Xt[xr][xs * 4] = p;                                           \
    } else {                                                                  \
      *(uint2*)&Xt[xr][xs * 4] = xh2[S];                                      \
    }                                                                         \
  } while (0)

#define DOMFMA                                                                \
  do {                                                                        \
    _Pragma("unroll") for (int kt = 0; kt < 2; kt++) {                        \
      bf16x8 a = *(const bf16x8*)&Wt[wv * 16 + L15][kt * 32 + q * 8];         \
      bf16x8 b = *(const bf16x8*)&Xt[L15][kt * 32 + q * 8];                   \
      acc = __builtin_amdgcn_mfma_f32_16x16x32_bf16(a, b, acc, 0, 0, 0);      \
    }                                                                         \
  } while (0)

  f32x4 acc = {};
  LOADW(0, 0);
  LOADX(0, 0);
  for (int k0 = 0; k0 < K; k0 += 128) {
    LOADW(1, k0 + 64);  // k0+64 < K always (K multiple of 128)
    LOADX(1, k0 + 64);
    STAGEW(0);
    STAGEX(0);
    __syncthreads();
    DOMFMA;
    __syncthreads();
    if (k0 + 128 < K) {
      LOADW(0, k0 + 128);
      LOADX(0, k0 + 128);
    }
    STAGEW(1);
    STAGEX(1);
    __syncthreads();
    DOMFMA;
    __syncthreads();
  }
#undef LOADW
#undef LOADX
#undef STAGEW
#undef STAGEX
#undef DOMFMA

  // epilogue: rows i_base+16*wv+q*4 .. +3, batch col b_base+L15
  {
    const int nrow = i_base + 16 * wv + q * 4;
    const float bi0 = bias[nrow], bi1 = bias[nrow + 1];
    const float bi2 = bias[nrow + 2], bi3 = bias[nrow + 3];
    const int b = b_base + L15;
    const float a0 = __builtin_amdgcn_rcpf(1.f + __expf(-(acc[0] + bi0)));
    const float a1 = __builtin_amdgcn_rcpf(1.f + __expf(-(acc[1] + bi1)));
    const float a2 = __builtin_amdgcn_rcpf(1.f + __expf(-(acc[2] + bi2)));
    const float a3 = __builtin_amdgcn_rcpf(1.f + __expf(-(acc[3] + bi3)));
    const float p0 = 0.5f * (a0 + a1), p1 = 0.5f * (a2 + a3);
    const int pidx = nrow >> 1;  // even
    if (out_bf16) {
      *(unsigned int*)&((unsigned short*)Y)[(size_t)b * Np + pidx] = pack2bf(p0, p1);
    } else {
      *(float2*)&((float*)Y)[(size_t)b * Np + pidx] = make_float2(p0, p1);
    }
  }
}

// ---------- MFMA LSTM (R27 body, measured 133.7 == R22's 133.5 within noise) -
// Structure FROZEN: R17 dense (205), R18 16-wave (200), R20 tail-fold (145),
// R24 dual-batch (206) regressed; R27 chain micro-cuts absorbed (no change).
// The step is pinned by the recurrent skeleton (barrier -> ds_read -> MFMA
// chain -> 2-deep trans -> h write) x 256; everything else hides under it.
#define TSTEPS 256

__device__ __forceinline__ float qb0(float x) {
  return __builtin_bit_cast(float, __builtin_amdgcn_mov_dpp(__builtin_bit_cast(int, x), 0x00, 0xf, 0xf, true));
}
__device__ __forceinline__ float qb1(float x) {
  return __builtin_bit_cast(float, __builtin_amdgcn_mov_dpp(__builtin_bit_cast(int, x), 0x55, 0xf, 0xf, true));
}
__device__ __forceinline__ float qb2(float x) {
  return __builtin_bit_cast(float, __builtin_amdgcn_mov_dpp(__builtin_bit_cast(int, x), 0xAA, 0xf, 0xf, true));
}
__device__ __forceinline__ float qb3(float x) {
  return __builtin_bit_cast(float, __builtin_amdgcn_mov_dpp(__builtin_bit_cast(int, x), 0xFF, 0xf, 0xf, true));
}

__global__ __launch_bounds__(512, 2) void lstm_mfma(
    const float* __restrict__ X, const _Float16* __restrict__ P,
    const float* __restrict__ Whh, const float* __restrict__ Wih,
    const float* __restrict__ b3, const float* __restrict__ Wout,
    const float* __restrict__ bout, float* __restrict__ out) {
  const int bat = blockIdx.x;
  const int t = threadIdx.x;
  const int w = t >> 6, lane = t & 63;
  const int quad = lane >> 4, c = lane & 15;
  const int TB = (w == 7) ? 21 : w * 3;   // tile base
  const int NT = (w == 7) ? 4 : 3;        // tiles this wave activates

  __shared__ __align__(16) _Float16 hbuf[2][128];
  __shared__ float xrow[TSTEPS];
  __shared__ float red[128];

  for (int i = t; i < TSTEPS; i += 512) xrow[i] = X[(size_t)bat * TSTEPS + i];
  if (t < 128) { hbuf[0][t] = (_Float16)0.f; hbuf[1][t] = (_Float16)0.f; }

#define LDA(J, KT) const f16x8 A##J##KT = \
    *(const f16x8*)&P[(size_t)((TB + J) * 16 + c) * 128 + (KT) * 32 + quad * 8];
  LDA(0,0) LDA(0,1) LDA(0,2)
  LDA(1,0) LDA(1,1) LDA(1,2)
  LDA(2,0) LDA(2,1) LDA(2,2)
  LDA(3,0) LDA(3,1) LDA(3,2)
#undef LDA

  // activation role: lane handles gate g of hid 4*(TB+J)+quad
  const bool act = (c < 4 * NT);
  const int J = c >> 2, g = c & 3;
  const int myhid = 4 * (TB + (act ? J : 0)) + quad;  // < 100
  const int grow = g * 100 + myhid;                   // gate-major row
  const float sc = (g == 2) ? TWOL2E : LOG2E;         // exp2 prescale
  const float u_ = Wih[grow] * sc;
  const float bz = b3[grow] * sc;
  const float4 wt0 = *(const float4*)&Whh[(size_t)grow * 100 + 96];  // k 96..99
  const float4 wt = make_float4(wt0.x * sc, wt0.y * sc, wt0.z * sc, wt0.w * sc);
  const float mm = (g == 2) ? 2.f : 1.f;   // g-gate is tanh = 2*sig(2z)-1
  const float dd = (g == 2) ? -1.f : 0.f;
  float cst = 0.f;
  __syncthreads();

#define SIG2(zz) __builtin_amdgcn_rcpf(1.f + __builtin_amdgcn_exp2f(-(zz)))
#define STEPB(HC, HN, XT)                                                      \
  {                                                                            \
    const _Float16* hc = (HC);                                                 \
    const f16x8 B0 = *(const f16x8*)&hc[0 * 32 + quad * 8];                    \
    const f16x8 B1 = *(const f16x8*)&hc[1 * 32 + quad * 8];                    \
    const f16x8 B2 = *(const f16x8*)&hc[2 * 32 + quad * 8];                    \
    const f16x4 ht = *(const f16x4*)&hc[96]; /* hoisted: hides under MFMAs */  \
    f32x4 z0 = {0.f,0.f,0.f,0.f}, z1 = z0, z2 = z0, z3 = z0;                   \
    { f32x4 za = z0, zb = z0;                                                  \
      za = __builtin_amdgcn_mfma_f32_16x16x32_f16(A00, B0, za, 0, 0, 0);       \
      zb = __builtin_amdgcn_mfma_f32_16x16x32_f16(A01, B1, zb, 0, 0, 0);       \
      za = __builtin_amdgcn_mfma_f32_16x16x32_f16(A02, B2, za, 0, 0, 0);       \
      z0 = za + zb; }                                                          \
    { f32x4 za = {0.f,0.f,0.f,0.f}, zb = za;                                   \
      za = __builtin_amdgcn_mfma_f32_16x16x32_f16(A10, B0, za, 0, 0, 0);       \
      zb = __builtin_amdgcn_mfma_f32_16x16x32_f16(A11, B1, zb, 0, 0, 0);       \
      za = __builtin_amdgcn_mfma_f32_16x16x32_f16(A12, B2, za, 0, 0, 0);       \
      z1 = za + zb; }                                                          \
    { f32x4 za = {0.f,0.f,0.f,0.f}, zb = za;                                   \
      za = __builtin_amdgcn_mfma_f32_16x16x32_f16(A20, B0, za, 0, 0, 0);       \
      zb = __builtin_amdgcn_mfma_f32_16x16x32_f16(A21, B1, zb, 0, 0, 0);       \
      za = __builtin_amdgcn_mfma_f32_16x16x32_f16(A22, B2, za, 0, 0, 0);       \
      z2 = za + zb; }                                                          \
    if (w == 7) {                                                              \
      f32x4 za = {0.f,0.f,0.f,0.f}, zb = za;                                   \
      za = __builtin_amdgcn_mfma_f32_16x16x32_f16(A30, B0, za, 0, 0, 0);       \
      zb = __builtin_amdgcn_mfma_f32_16x16x32_f16(A31, B1, zb, 0, 0, 0);       \
      za = __builtin_amdgcn_mfma_f32_16x16x32_f16(A32, B2, za, 0, 0, 0);       \
      z3 = za + zb; }                                                          \
    if (act) {                                                                 \
      const f32x4 zt = (J == 0) ? z0 : (J == 1) ? z1 : (J == 2) ? z2 : z3;     \
      const float zsel = (g == 0) ? zt[0] : (g == 1) ? zt[1]                   \
                       : (g == 2) ? zt[2] : zt[3];                             \
      const float t0 = fmaf(wt.x, (float)ht[0], fmaf(wt.y, (float)ht[1], bz)); \
      const float t1 = fmaf(wt.z, (float)ht[2],                                \
                            fmaf(wt.w, (float)ht[3], u_ * (XT)));              \
      const float zs = (zsel + t0) + t1;                                       \
      const float a = mm * SIG2(zs) + dd;                                      \
      const float ai = qb0(a), af = qb1(a), ag = qb2(a), ao = qb3(a);          \
      cst = fmaf(af, cst, ai * ag);                                            \
      const float th = 2.f * SIG2(TWOL2E * cst) - 1.f;                         \
      if (g == 0) (HN)[myhid] = (_Float16)(ao * th);                           \
    }                                                                          \
    __syncthreads();                                                           \
  }

  for (int step = 0; step < TSTEPS; step += 2) {
    STEPB(hbuf[0], hbuf[1], xrow[step]);
    STEPB(hbuf[1], hbuf[0], xrow[step + 1]);
  }
#undef STEPB
#undef SIG2

  // out[bat] = dot(h_final, Wout) + bout; final h in hbuf[0]
  if (t < 128) {
    float a = 0.f;
    if (t < 100) a = (float)hbuf[0][t] * Wout[t];
    red[t] = a;
  }
  __syncthreads();
  if (t == 0) {
    float s = 0.f;
#pragma unroll
    for (int k = 0; k < 128; k++) s += red[k];
    out[bat] = s + bout[0];
  }
}

// ---------- launch: 3 dispatches (prep rides gemm2's idle CUs) ----------
extern "C" void kernel_launch(void* const* d_in, const int* in_sizes, int n_in,
                              void* d_out, int out_size, void* d_ws, size_t ws_size,
                              hipStream_t stream) {
  const float* x    = (const float*)d_in[0];   // (256,1024)
  const float* W1L  = (const float*)d_in[3];   // (1024,1024)
  const float* b1L  = (const float*)d_in[4];
  const float* W2L  = (const float*)d_in[7];   // (512,512)
  const float* b2L  = (const float*)d_in[8];
  const float* Wih3 = (const float*)d_in[15];  // (400,1)
  const float* Whh3 = (const float*)d_in[16];  // (400,100)
  const float* b3   = (const float*)d_in[17];  // (400,)
  const float* Wout = (const float*)d_in[18];  // (1,100)
  const float* bout = (const float*)d_in[19];  // (1,)
  float* out = (float*)d_out;                  // (256,)

  unsigned short* xl1b = (unsigned short*)d_ws;        // 256x512 bf16
  float* xl2 = (float*)(xl1b + (size_t)256 * 512);     // 256x256 f32
  _Float16* P = (_Float16*)(xl2 + (size_t)256 * 256);  // 400x128 fp16

  gemm_mfma_sig_pool<1, 1, 0, 16><<<dim3(16, 16), 256, 0, stream>>>(
      W1L, b1L, x, xl1b, 1024, 512, 1, nullptr, nullptr, nullptr);
  // gemm2 (128 blocks) + prep (16 blocks) share one dispatch: prep runs on
  // CUs gemm2 leaves idle. P is consumed only by lstm (stream-ordered).
  gemm_mfma_sig_pool<1, 0, 1, 8><<<dim3(9, 16), 256, 0, stream>>>(
      W2L, b2L, xl1b, xl2, 512, 256, 0, Whh3, b3, P);
  lstm_mfma<<<256, 512, 0, stream>>>(xl2, P, Whh3, Wih3, b3, Wout, bout, out);
}